// Round 5
// baseline (113.081 us; speedup 1.0000x reference)
//
#include <hip/hip_runtime.h>
#include <hip/hip_bf16.h>
#include <hip/hip_cooperative_groups.h>

namespace cg = cooperative_groups;

// EdgeConv: B=8, C=64, N=4096, K=16, O=64
// h[b,n,k,:] = relu(x_i @ (Wa-Wb) + x_j @ Wb + bias); out = max_k h
// K=128 augmented-row MFMA: A row e = [x_i | x_j_e], B = Wmod[128][64].
// Primary: single cooperative kernel (phase1 transpose+W-prep, grid.sync, phase2 gather+MFMA).
// Fallback (if coop launch rejected): proven 2-kernel path.

#define BB 8
#define CC 64
#define NN 4096
#define KK 16
#define OO 64

typedef __bf16 bf16x8 __attribute__((ext_vector_type(8)));
typedef float f32x4 __attribute__((ext_vector_type(4)));

union Frag { int4 i; bf16x8 v; };
union Pack8 { int4 i; __hip_bfloat16 h[8]; };

static constexpr size_t XTB_ELEMS = (size_t)BB * NN * CC;  // 4 MB bf16
static constexpr int GRID = 512;                           // 2 tiles of 32 nodes per block
static constexpr int NXT = BB * (NN / 64);                 // fallback prep blocks

// ------------------------- fused cooperative kernel -------------------------
__global__ __launch_bounds__(256, 2) void edgeconv_fused(
    const float* __restrict__ x, const int* __restrict__ ei,
    const float* __restrict__ W, const float* __restrict__ bias,
    float* __restrict__ out,
    __hip_bfloat16* __restrict__ xtb, __hip_bfloat16* __restrict__ wfrag) {
    // 16 KB scratch, time-shared: phase1 transpose tile -> phase2 W-stage -> output tile
    __shared__ int4 smem[1024];
    __shared__ int4 xil[2][32][8];      // 8 KB: both tiles' x_i rows
    float (*scr)[33] = (float(*)[33])smem;      // [64][33] = 8448 B
    int4 (*wfl)[64] = (int4(*)[64])smem;        // [16][64] = 16384 B

    int t = threadIdx.x, w = t >> 6, l = t & 63;
    int bid = blockIdx.x;
    int T0 = bid * 2;                   // tiles T0, T0+1 (128 tiles per batch)
    int b = T0 >> 7;
    int lg = l >> 4, le = l & 15;

    // ---------- phase 1: transpose x[b,C,n-tile] -> xtb[b,n,C] bf16 ----------
    const float* xb = x + (size_t)b * CC * NN;
    int4* xt4w = (int4*)xtb;
    #pragma unroll
    for (int nt = 0; nt < 2; ++nt) {
        int n0 = ((T0 + nt) & 127) << 5;
        #pragma unroll
        for (int it = 0; it < 8; ++it) {
            int idx = it * 256 + t;
            int c = idx >> 5, nn = idx & 31;
            scr[c][nn] = xb[c * NN + n0 + nn];          // coalesced along n
        }
        __syncthreads();
        {
            int nl = t >> 3, g = t & 7;
            Pack8 u;
            #pragma unroll
            for (int k2 = 0; k2 < 8; ++k2) u.h[k2] = __float2bfloat16(scr[g * 8 + k2][nl]);
            xil[nt][nl][g] = u.i;                       // keep own rows in LDS
            xt4w[((size_t)b * NN + n0 + nl) * 8 + g] = u.i;
        }
        __syncthreads();
    }

    // blocks 0..31 build Wmod = [[Wa-Wb],[Wb]] in MFMA B-fragment order
    if (bid < 32 && t < 32) {
        int fi = bid * 32 + t;          // int4 index 0..1023
        int lane = fi & 63, ot = (fi >> 6) & 3, s = fi >> 8;
        Pack8 u;
        #pragma unroll
        for (int j = 0; j < 8; ++j) {
            int kdim = s * 32 + (lane >> 4) * 8 + j;
            int o = ot * 16 + (lane & 15);
            float v = (kdim < 64) ? (W[kdim * OO + o] - W[(kdim + 64) * OO + o])
                                  : W[kdim * OO + o];
            u.h[j] = __float2bfloat16(v);
        }
        ((int4*)wfrag)[fi] = u.i;
    }

    // prefetch edge indices (latency hides behind the grid sync)
    const int* srcp = ei + (size_t)b * NN * KK;         // ei[0][b]
    int vidx[2][8];
    #pragma unroll
    for (int nt = 0; nt < 2; ++nt) {
        int nbase = (((T0 + nt) & 127) << 5) + w * 8;
        #pragma unroll
        for (int i = 0; i < 8; ++i) vidx[nt][i] = srcp[(nbase + i) * KK + le];
    }
    float bv[4];
    #pragma unroll
    for (int ot = 0; ot < 4; ++ot) bv[ot] = bias[ot * 16 + le];

    __threadfence();
    cg::this_grid().sync();

    // ---------- phase 2: stage W frags, MFMA gather loop per tile ----------
    const int4* wf4 = (const int4*)wfrag;
    #pragma unroll
    for (int i = 0; i < 4; ++i) {
        int idx = i * 256 + t;
        wfl[idx >> 6][idx & 63] = wf4[idx];
    }
    __syncthreads();

    Frag wf[4][4];
    #pragma unroll
    for (int s = 0; s < 4; ++s)
        #pragma unroll
        for (int ot = 0; ot < 4; ++ot)
            wf[s][ot].i = wfl[s * 4 + ot][l];
    __syncthreads();                    // smem now free -> reuse as output tile

    const int4* xt4 = (const int4*)(xtb + (size_t)b * NN * CC);
    float* ob = out + (size_t)b * OO * NN;

    #pragma unroll
    for (int nt = 0; nt < 2; ++nt) {
        int n0 = ((T0 + nt) & 127) << 5;

        Frag aj[2][2];
        aj[0][0].i = xt4[(size_t)vidx[nt][0] * 8 + lg];
        aj[0][1].i = xt4[(size_t)vidx[nt][0] * 8 + 4 + lg];

        #pragma unroll
        for (int i = 0; i < 8; ++i) {
            if (i < 7) {
                int v = vidx[nt][i + 1];
                aj[(i + 1) & 1][0].i = xt4[(size_t)v * 8 + lg];
                aj[(i + 1) & 1][1].i = xt4[(size_t)v * 8 + 4 + lg];
            }
            int nl = w * 8 + i;
            Frag ai0, ai1;
            ai0.i = xil[nt][nl][lg];        // LDS broadcast
            ai1.i = xil[nt][nl][4 + lg];

            f32x4 acc[4];
            #pragma unroll
            for (int ot = 0; ot < 4; ++ot) acc[ot] = f32x4{bv[ot], bv[ot], bv[ot], bv[ot]};

            #pragma unroll
            for (int ot = 0; ot < 4; ++ot) {
                acc[ot] = __builtin_amdgcn_mfma_f32_16x16x32_bf16(ai0.v, wf[0][ot].v, acc[ot], 0, 0, 0);
                acc[ot] = __builtin_amdgcn_mfma_f32_16x16x32_bf16(ai1.v, wf[1][ot].v, acc[ot], 0, 0, 0);
                acc[ot] = __builtin_amdgcn_mfma_f32_16x16x32_bf16(aj[i & 1][0].v, wf[2][ot].v, acc[ot], 0, 0, 0);
                acc[ot] = __builtin_amdgcn_mfma_f32_16x16x32_bf16(aj[i & 1][1].v, wf[3][ot].v, acc[ot], 0, 0, 0);
            }

            // D layout: col=lane&15 (=o), row=(lane>>4)*4+reg (=edge). Max over 16 edges.
            #pragma unroll
            for (int ot = 0; ot < 4; ++ot) {
                float r = fmaxf(fmaxf(acc[ot][0], acc[ot][1]), fmaxf(acc[ot][2], acc[ot][3]));
                r = fmaxf(r, __shfl_xor(r, 16));
                r = fmaxf(r, __shfl_xor(r, 32));
                r = fmaxf(r, 0.0f);          // relu commutes with max
                if (l < 16) scr[ot * 16 + l][nl] = r;
            }
        }
        __syncthreads();
        #pragma unroll
        for (int it = 0; it < 8; ++it) {
            int idx = it * 256 + t;
            int o = idx >> 5, nn = idx & 31;
            ob[(size_t)o * NN + n0 + nn] = scr[o][nn];   // coalesced
        }
        __syncthreads();
    }
}

// ------------------------- fallback: proven 2-kernel path -------------------------
__global__ __launch_bounds__(256) void prep(const float* __restrict__ x,
                                            const float* __restrict__ W,
                                            __hip_bfloat16* __restrict__ xtb,
                                            __hip_bfloat16* __restrict__ wfrag) {
    int t = threadIdx.x;
    if (blockIdx.x == NXT) {
        for (int idx = t; idx < 4 * 4 * 64 * 8; idx += 256) {
            int j = idx & 7, lane = (idx >> 3) & 63, ot = (idx >> 9) & 3, s = idx >> 11;
            int kdim = s * 32 + (lane >> 4) * 8 + j;
            int o = ot * 16 + (lane & 15);
            float v = (kdim < 64) ? (W[kdim * OO + o] - W[(kdim + 64) * OO + o])
                                  : W[kdim * OO + o];
            wfrag[idx] = __float2bfloat16(v);
        }
        return;
    }
    __shared__ float tile[64][65];
    int b = blockIdx.x >> 6;
    int n0 = (blockIdx.x & 63) << 6;
    const float* xb = x + (size_t)b * CC * NN;
    #pragma unroll
    for (int it = 0; it < 16; ++it) {
        int idx = it * 256 + t;
        int c = idx >> 6, nn = idx & 63;
        tile[c][nn] = xb[c * NN + n0 + nn];
    }
    __syncthreads();
    __hip_bfloat16* xo = xtb + ((size_t)b * NN + n0) * CC;
    #pragma unroll
    for (int it = 0; it < 16; ++it) {
        int idx = it * 256 + t;
        int nl = idx >> 6, c = idx & 63;
        xo[nl * CC + c] = __float2bfloat16(tile[c][nl]);
    }
}

__global__ __launch_bounds__(256, 3) void edgeconv_main(
    const int* __restrict__ ei, const float* __restrict__ bias,
    const __hip_bfloat16* __restrict__ xtb, const __hip_bfloat16* __restrict__ wfrag,
    float* __restrict__ out) {
    __shared__ int4 wfl[16][64];
    __shared__ int4 xil[32][8];
    __shared__ float otile[64][33];

    int t = threadIdx.x;
    int w = t >> 6, l = t & 63;
    int b = blockIdx.x >> 7;
    int n0 = (blockIdx.x & 127) << 5;

    const int4* wf4 = (const int4*)wfrag;
    #pragma unroll
    for (int i = 0; i < 4; ++i) {
        int idx = i * 256 + t;
        wfl[idx >> 6][idx & 63] = wf4[idx];
    }
    const int4* xt4 = (const int4*)(xtb + (size_t)b * NN * CC);
    xil[t >> 3][t & 7] = xt4[(n0 + (t >> 3)) * 8 + (t & 7)];

    float bv[4];
    #pragma unroll
    for (int ot = 0; ot < 4; ++ot) bv[ot] = bias[ot * 16 + (l & 15)];

    const int* srcp = ei + (size_t)b * NN * KK;
    int lg = l >> 4, le = l & 15;
    int nbase = n0 + w * 8;

    int vidx[8];
    #pragma unroll
    for (int i = 0; i < 8; ++i) vidx[i] = srcp[(nbase + i) * KK + le];

    __syncthreads();

    Frag wf[4][4];
    #pragma unroll
    for (int s = 0; s < 4; ++s)
        #pragma unroll
        for (int ot = 0; ot < 4; ++ot)
            wf[s][ot].i = wfl[s * 4 + ot][l];

    Frag aj[2][2];
    aj[0][0].i = xt4[(size_t)vidx[0] * 8 + lg];
    aj[0][1].i = xt4[(size_t)vidx[0] * 8 + 4 + lg];

    #pragma unroll
    for (int i = 0; i < 8; ++i) {
        if (i < 7) {
            int v = vidx[i + 1];
            aj[(i + 1) & 1][0].i = xt4[(size_t)v * 8 + lg];
            aj[(i + 1) & 1][1].i = xt4[(size_t)v * 8 + 4 + lg];
        }
        int nl = w * 8 + i;
        Frag ai0, ai1;
        ai0.i = xil[nl][lg];
        ai1.i = xil[nl][4 + lg];

        f32x4 acc[4];
        #pragma unroll
        for (int ot = 0; ot < 4; ++ot) acc[ot] = f32x4{bv[ot], bv[ot], bv[ot], bv[ot]};

        #pragma unroll
        for (int ot = 0; ot < 4; ++ot) {
            acc[ot] = __builtin_amdgcn_mfma_f32_16x16x32_bf16(ai0.v, wf[0][ot].v, acc[ot], 0, 0, 0);
            acc[ot] = __builtin_amdgcn_mfma_f32_16x16x32_bf16(ai1.v, wf[1][ot].v, acc[ot], 0, 0, 0);
            acc[ot] = __builtin_amdgcn_mfma_f32_16x16x32_bf16(aj[i & 1][0].v, wf[2][ot].v, acc[ot], 0, 0, 0);
            acc[ot] = __builtin_amdgcn_mfma_f32_16x16x32_bf16(aj[i & 1][1].v, wf[3][ot].v, acc[ot], 0, 0, 0);
        }

        #pragma unroll
        for (int ot = 0; ot < 4; ++ot) {
            float r = fmaxf(fmaxf(acc[ot][0], acc[ot][1]), fmaxf(acc[ot][2], acc[ot][3]));
            r = fmaxf(r, __shfl_xor(r, 16));
            r = fmaxf(r, __shfl_xor(r, 32));
            r = fmaxf(r, 0.0f);
            if (l < 16) otile[ot * 16 + l][nl] = r;
        }
    }
    __syncthreads();
    float* ob = out + (size_t)b * OO * NN;
    #pragma unroll
    for (int it = 0; it < 8; ++it) {
        int idx = it * 256 + t;
        int o = idx >> 5, nn = idx & 31;
        ob[(size_t)o * NN + n0 + nn] = otile[o][nn];
    }
}

extern "C" void kernel_launch(void* const* d_in, const int* in_sizes, int n_in,
                              void* d_out, int out_size, void* d_ws, size_t ws_size,
                              hipStream_t stream) {
    const float* x    = (const float*)d_in[0];   // [B,C,N,1] f32
    const int*   ei   = (const int*)d_in[1];     // [2,B,N,K] i32
    const float* W    = (const float*)d_in[2];   // [128,64] f32
    const float* bias = (const float*)d_in[3];   // [64] f32
    float* out = (float*)d_out;                  // [B,O,N,1] f32

    __hip_bfloat16* xtb   = (__hip_bfloat16*)d_ws;   // 4 MB
    __hip_bfloat16* wfrag = xtb + XTB_ELEMS;         // +16 KB

    void* args[] = { (void*)&x, (void*)&ei, (void*)&W, (void*)&bias,
                     (void*)&out, (void*)&xtb, (void*)&wfrag };
    hipError_t e = hipLaunchCooperativeKernel((const void*)edgeconv_fused,
                                              dim3(GRID), dim3(256), args, 0, stream);
    if (e != hipSuccess) {
        (void)hipGetLastError();   // clear sticky error, fall back to 2-kernel path
        hipLaunchKernelGGL(prep, dim3(NXT + 1), dim3(256), 0, stream, x, W, xtb, wfrag);
        hipLaunchKernelGGL(edgeconv_main, dim3(BB * (NN / 32)), dim3(256), 0, stream,
                           ei, bias, xtb, wfrag, out);
    }
}